// Round 14
// baseline (129.058 us; speedup 1.0000x reference)
//
#include <hip/hip_runtime.h>
#include <hip/hip_bf16.h>
#include <hip/hip_fp8.h>
#include <stdint.h>

#define NROW 8192
#define DIM  512
#define BM   128
#define BN   128
#define BKB  128                  // K-step in BYTES (=128 fp8 elements)
#define NTK  (DIM / BKB)          // 4 K-steps
#define NT   (NROW / BM)          // 64 tile rows/cols
#define NBLK (NT * (NT + 1) / 2)  // 2080 upper-triangular tiles (= 8 * 260)

typedef float f32x4 __attribute__((ext_vector_type(4)));

__device__ __forceinline__ float fast_sqrtf(float x) {
    return __builtin_amdgcn_sqrtf(x);   // raw v_sqrt_f32; tolerance is 1.5e-2
}

__device__ __forceinline__ unsigned char f32_to_e4m3(float f) {
    __hip_fp8_e4m3 q(f);                // OCP e4m3fn, RNE + satfinite
    return (unsigned char)q.__x;
}

// ---------------------------------------------------------------------------
// prep: blocks 0..2047: z (fp32) -> zq (fp8 e4m3), sq[i] = ||z_i||^2 (fp32,
// exact norms — only the cross-dot is quantized). block 2048: hist via LDS
// atomics (R7-verified) + zero init (replaces memset dispatch).
// ---------------------------------------------------------------------------
__global__ __launch_bounds__(256) void prep_kernel(
    const float* __restrict__ z, const int* __restrict__ labels,
    unsigned char* __restrict__ zq, float* __restrict__ sq,
    int* __restrict__ hist, float* __restrict__ totals,
    int* __restrict__ done_ctr)
{
    if (blockIdx.x == NROW / 4) {            // histogram / init block
        __shared__ int lh[64];
        const int tid = threadIdx.x;
        if (tid < 64) lh[tid] = 0;
        __syncthreads();
        for (int i = tid; i < NROW; i += 256)
            atomicAdd(&lh[labels[i]], 1);    // LDS atomics: no XCD ping-pong
        __syncthreads();
        if (tid < 64) hist[tid] = lh[tid];
        if (tid == 64) { totals[0] = 0.f; totals[1] = 0.f; }
        if (tid == 65) { *done_ctr = 0; }
        return;
    }

    const int lane = threadIdx.x & 63;
    const int wave = threadIdx.x >> 6;
    const int row  = blockIdx.x * 4 + wave;

    const float4* zr = (const float4*)(z + (size_t)row * DIM);
    float4 v0 = zr[lane * 2 + 0];
    float4 v1 = zr[lane * 2 + 1];
    float s = v0.x*v0.x + v0.y*v0.y + v0.z*v0.z + v0.w*v0.w
            + v1.x*v1.x + v1.y*v1.y + v1.z*v1.z + v1.w*v1.w;

    union { unsigned char b[8]; int2 v; } pk;
    pk.b[0] = f32_to_e4m3(v0.x); pk.b[1] = f32_to_e4m3(v0.y);
    pk.b[2] = f32_to_e4m3(v0.z); pk.b[3] = f32_to_e4m3(v0.w);
    pk.b[4] = f32_to_e4m3(v1.x); pk.b[5] = f32_to_e4m3(v1.y);
    pk.b[6] = f32_to_e4m3(v1.z); pk.b[7] = f32_to_e4m3(v1.w);
    ((int2*)(zq + (size_t)row * DIM))[lane] = pk.v;   // bytes k..k+7 in order

    #pragma unroll
    for (int sft = 1; sft < 64; sft <<= 1) s += __shfl_xor(s, sft);
    if (lane == 0) sq[row] = s;
}

// ---------------------------------------------------------------------------
// tile: one 128x128 Gram tile (upper triangle) via 16x16x32 FP8 MFMA.
// R13: CHUNK-MAJOR LDS layout [c2 = k/16][row][16B] (2048 B per chunk):
//  - staging dest = (r*2 + tid>>7)*2048 + (tid&127)*16 -> per wave this is
//    uniform-base + lane*16 (tid>>7 wave-uniform) — satisfies the
//    global_load_lds linear-dest constraint that R10's padded rows broke
//    (rule #21/m173: that was the R10 correctness bug).
//  - source = 16 contiguous global bytes (row = tid&127, k = c2*16..+16).
//  - ds_read fragment addr = ONE base VGPR per matrix + compile-time
//    offset immediate (kk4*4096 + m*256): no XOR, no per-read VALU.
// (256,3): 3 blocks/CU (R8's (256,4) spilled). No global atomics.
// ---------------------------------------------------------------------------
template <bool DIAG>
__device__ __forceinline__ void epilogue(
    int tid, int lane, int wm, int wn, int row0, int col0, bool offdiag,
    const f32x4 acc[4][4], const float* __restrict__ sq,
    const int* __restrict__ labels, unsigned char* lds,
    float* __restrict__ partial_pos, float* __restrict__ partial_neg)
{
    const int colbase = col0 + wn * 64;
    const int hi = lane >> 4;
    float csq[4]; int clb[4];
    #pragma unroll
    for (int n = 0; n < 4; ++n) {
        int cg = colbase + n * 16 + (lane & 15);
        csq[n] = sq[cg];
        clb[n] = labels[cg];
    }
    float cpos[4] = {0.f, 0.f, 0.f, 0.f};
    float ctot[4] = {0.f, 0.f, 0.f, 0.f};

    float* rp = (float*)lds;       // [wn*128 + row_local]  256 f
    float* rn = rp + 256;          // 256 f
    float* cp = rp + 512;          // [wm*128 + col_local]  256 f
    float* cn = rp + 768;          // 256 f

    #pragma unroll
    for (int m = 0; m < 4; ++m) {
        #pragma unroll
        for (int r = 0; r < 4; ++r) {
            const int rowl = wm * 64 + m * 16 + hi * 4 + r;
            const int rg = row0 + rowl;
            const float rs = sq[rg];
            const int   rl = labels[rg];
            float pos = 0.f, tot = 0.f;
            #pragma unroll
            for (int n = 0; n < 4; ++n) {
                float d2   = rs + csq[n] - 2.0f * acc[m][n][r];
                float dist = d2 > 0.f ? fast_sqrtf(d2) : 0.f;
                if (DIAG) {
                    int cg = colbase + n * 16 + (lane & 15);
                    if (cg == rg) dist = 0.f;      // exact-zero diagonal
                }
                float dp = (rl == clb[n]) ? dist : 0.f;
                pos += dp;  tot += dist;
                cpos[n] += dp;  ctot[n] += dist;   // column sums (symmetry)
            }
            #pragma unroll
            for (int s = 1; s < 16; s <<= 1) {
                pos += __shfl_xor(pos, s);
                tot += __shfl_xor(tot, s);
            }
            if ((lane & 15) == 0) {
                rp[wn * 128 + rowl] = pos;
                rn[wn * 128 + rowl] = tot - pos;
            }
        }
    }

    #pragma unroll
    for (int n = 0; n < 4; ++n) {
        cpos[n] += __shfl_xor(cpos[n], 16);
        cpos[n] += __shfl_xor(cpos[n], 32);
        ctot[n] += __shfl_xor(ctot[n], 16);
        ctot[n] += __shfl_xor(ctot[n], 32);
        if (lane < 16) {
            int coll = wn * 64 + n * 16 + lane;
            cp[wm * 128 + coll] = cpos[n];
            cn[wm * 128 + coll] = ctot[n] - cpos[n];
        }
    }
    __syncthreads();

    // unique-writer plain stores (no atomics, no zero-init needed)
    const int tn = col0 / BN, tm = row0 / BM;
    if (tid < 128) {
        float p  = rp[tid] + rp[128 + tid];
        float nn = rn[tid] + rn[128 + tid];
        partial_pos[(size_t)tn * NROW + row0 + tid] = p;
        partial_neg[(size_t)tn * NROW + row0 + tid] = nn;
        if (offdiag) {
            float p2 = cp[tid] + cp[128 + tid];
            float n2 = cn[tid] + cn[128 + tid];
            partial_pos[(size_t)tm * NROW + col0 + tid] = p2;
            partial_neg[(size_t)tm * NROW + col0 + tid] = n2;
        }
    }
}

__global__ __launch_bounds__(256, 3) void tile_kernel(
    const unsigned char* __restrict__ zq,
    const float* __restrict__ sq, const int* __restrict__ labels,
    float* __restrict__ partial_pos, float* __restrict__ partial_neg)
{
    __shared__ unsigned char As[8 * 2048];  // 16 KiB: [c2][row][16B]
    __shared__ unsigned char Bs[8 * 2048];  // 16 KiB

    const int tid  = threadIdx.x;
    const int lane = tid & 63;
    const int wave = tid >> 6;
    const int wm = wave >> 1;   // 0..1 -> 64-row half
    const int wn = wave & 1;    // 0..1 -> 64-col half

    // XCD-chunked bijective remap (2080 = 8*260), then triangular decode
    const int bid  = (int)blockIdx.x;
    int bidx = (bid & 7) * (NBLK / 8) + (bid >> 3);
    int tm = 0, rem = bidx;
    while (rem >= NT - tm) { rem -= NT - tm; ++tm; }
    const int tn = tm + rem;
    const int row0 = tm * BM;
    const int col0 = tn * BN;
    const bool offdiag = (tm != tn);

    f32x4 acc[4][4];
    #pragma unroll
    for (int m = 0; m < 4; ++m)
        #pragma unroll
        for (int n = 0; n < 4; ++n)
            acc[m][n] = (f32x4){0.f, 0.f, 0.f, 0.f};

    // staging: thread tid, call r writes 16 B of chunk c2 = r*2 + (tid>>7),
    // row = tid&127. Per-wave dest = uniform base + lane*16 (linear ✓);
    // source = 16 contiguous global bytes (k = c2*16..+16) ✓.
    const int srow = tid & 127;
    const int c2b  = tid >> 7;                       // wave-uniform (0/1)
    const int dst0 = c2b * 2048 + srow * 16;
    const unsigned char* baseA = zq + (size_t)(row0 + srow) * DIM + c2b * 16;
    const unsigned char* baseB = zq + (size_t)(col0 + srow) * DIM + c2b * 16;

    // ds_read base: ONE address register per matrix; all 16 reads use
    // compile-time offset immediates (kk4*4096 + m*256 <= 13056).
    const int hibase = ((lane >> 5) << 11) + (((lane >> 4) & 1) << 3);
    const unsigned char* apv = As + wm * 1024 + (lane & 15) * 16 + hibase;
    const unsigned char* bpv = Bs + wn * 1024 + (lane & 15) * 16 + hibase;

    #pragma unroll
    for (int t = 0; t < NTK; ++t) {
        const int k0 = t * BKB;
        #pragma unroll
        for (int r = 0; r < 4; ++r) {
            __builtin_amdgcn_global_load_lds(
                (const __attribute__((address_space(1))) void*)(baseA + k0 + r * 32),
                (__attribute__((address_space(3))) void*)(As + r * 4096 + dst0),
                16, 0, 0);
            __builtin_amdgcn_global_load_lds(
                (const __attribute__((address_space(1))) void*)(baseB + k0 + r * 32),
                (__attribute__((address_space(3))) void*)(Bs + r * 4096 + dst0),
                16, 0, 0);
        }
        __syncthreads();   // vmcnt(0) drain; hidden by the other 2 blocks/CU

        #pragma unroll
        for (int kk4 = 0; kk4 < 4; ++kk4) {             // 4 x K=32 fp8 MFMA
            long bg[4];
            #pragma unroll
            for (int n = 0; n < 4; ++n)
                bg[n] = *(const long*)(bpv + kk4 * 4096 + n * 256);
            #pragma unroll
            for (int m = 0; m < 4; ++m) {
                long af = *(const long*)(apv + kk4 * 4096 + m * 256);
                #pragma unroll
                for (int n = 0; n < 4; ++n)
                    acc[m][n] = __builtin_amdgcn_mfma_f32_16x16x32_fp8_fp8(
                        af, bg[n], acc[m][n], 0, 0, 0);
            }
        }
        __syncthreads();   // LDS reuse safety for next STAGE
    }

    if (offdiag)
        epilogue<false>(tid, lane, wm, wn, row0, col0, true,  acc, sq, labels,
                        As, partial_pos, partial_neg);
    else
        epilogue<true >(tid, lane, wm, wn, row0, col0, false, acc, sq, labels,
                        As, partial_pos, partial_neg);
}

// ---------------------------------------------------------------------------
// row loss: sum the 64 per-slot partials, margin/relu/reduce; the LAST block
// (device-scope counter) computes the final quotient (saves a dispatch).
// ---------------------------------------------------------------------------
__global__ __launch_bounds__(256) void rowloss_kernel(
    const float* __restrict__ partial_pos, const float* __restrict__ partial_neg,
    const int* __restrict__ labels, const int* __restrict__ hist,
    float* __restrict__ totals, int* __restrict__ done_ctr,
    float* __restrict__ out)
{
    const int i = blockIdx.x * 256 + threadIdx.x;
    float ps = 0.f, ns = 0.f;
    #pragma unroll 8
    for (int s = 0; s < NT; ++s) {
        ps += partial_pos[(size_t)s * NROW + i];
        ns += partial_neg[(size_t)s * NROW + i];
    }
    const float pc = (float)hist[labels[i]];        // includes self
    const float nc = (float)NROW - pc;
    const float pm = ps / fmaxf(pc, 1.f);
    const float nm = ns / fmaxf(nc, 1.f);
    const bool valid = (pc > 1.f) && (nc > 0.f);
    float t = valid ? fmaxf(pm - nm + 1.0f, 0.f) : 0.f;
    float c = valid ? 1.f : 0.f;
    #pragma unroll
    for (int s = 1; s < 64; s <<= 1) {
        t += __shfl_xor(t, s);
        c += __shfl_xor(c, s);
    }
    __shared__ float blk[8];  // 4 waves x {t,c}
    const int wv = threadIdx.x >> 6;
    if ((threadIdx.x & 63) == 0) { blk[wv] = t; blk[4 + wv] = c; }
    __syncthreads();
    if (threadIdx.x == 0) {
        atomicAdd(&totals[0], blk[0] + blk[1] + blk[2] + blk[3]);
        atomicAdd(&totals[1], blk[4] + blk[5] + blk[6] + blk[7]);
        __threadfence();
        int prev = atomicAdd(done_ctr, 1);
        if (prev == (int)gridDim.x - 1) {
            float tt = atomicAdd(&totals[0], 0.f);   // coherent read
            float cc = atomicAdd(&totals[1], 0.f);
            out[0] = tt / fmaxf(cc, 1.f);
        }
    }
}

// ---------------------------------------------------------------------------
extern "C" void kernel_launch(void* const* d_in, const int* in_sizes, int n_in,
                              void* d_out, int out_size, void* d_ws, size_t ws_size,
                              hipStream_t stream) {
    (void)in_sizes; (void)n_in; (void)out_size; (void)ws_size;
    const float* z      = (const float*)d_in[0];
    const int*   labels = (const int*)d_in[1];
    float*       out    = (float*)d_out;

    char* ws = (char*)d_ws;
    float* partial_pos = (float*)(ws);                      // 2 MiB (64 x 8192 f32)
    float* partial_neg = (float*)(ws + 2097152);            // 2 MiB
    int*   hist     = (int*)  (ws + 4194304);               // 256 B
    float* totals   = (float*)(ws + 4194560);               // 8 B
    int*   done_ctr = (int*)  (ws + 4194568);               // 4 B
    unsigned char* zq = (unsigned char*)(ws + 4194816);     // 4 MiB (fp8)
    float* sq       = (float*)(ws + 4194816 + (size_t)NROW * DIM); // 32 KiB

    // no memset: prep's extra block zeroes hist/totals/done_ctr;
    // partials are written exactly once per launch.
    prep_kernel    <<<NROW / 4 + 1, 256, 0, stream>>>(z, labels, zq, sq, hist,
                                                      totals, done_ctr);
    tile_kernel    <<<NBLK, 256, 0, stream>>>(zq, sq, labels, partial_pos, partial_neg);
    rowloss_kernel <<<NROW / 256, 256, 0, stream>>>(partial_pos, partial_neg, labels,
                                                    hist, totals, done_ctr, out);
}

// Round 15
// 106.199 us; speedup vs baseline: 1.2153x; 1.2153x over previous
//
#include <hip/hip_runtime.h>
#include <hip/hip_bf16.h>
#include <hip/hip_fp8.h>
#include <stdint.h>

#define NROW 8192
#define DIM  512
#define BM   128
#define BN   128
#define BKB  128                  // K-step in BYTES (=128 fp8 elements)
#define NTK  (DIM / BKB)          // 4 K-steps
#define NT   (NROW / BM)          // 64 tile rows/cols
#define NBLK (NT * (NT + 1) / 2)  // 2080 upper-triangular tiles (= 8 * 260)

typedef float f32x4 __attribute__((ext_vector_type(4)));

__device__ __forceinline__ float fast_sqrtf(float x) {
    return __builtin_amdgcn_sqrtf(x);   // raw v_sqrt_f32; tolerance is 1.5e-2
}

__device__ __forceinline__ unsigned char f32_to_e4m3(float f) {
    __hip_fp8_e4m3 q(f);                // OCP e4m3fn, RNE + satfinite
    return (unsigned char)q.__x;
}

// ---------------------------------------------------------------------------
// prep: blocks 0..2047: z (fp32) -> zq (fp8 e4m3), sq[i] = ||z_i||^2 (fp32,
// exact norms — only the cross-dot is quantized). block 2048: hist via LDS
// atomics (R7-verified) + zero init (replaces memset dispatch).
// ---------------------------------------------------------------------------
__global__ __launch_bounds__(256) void prep_kernel(
    const float* __restrict__ z, const int* __restrict__ labels,
    unsigned char* __restrict__ zq, float* __restrict__ sq,
    int* __restrict__ hist, float* __restrict__ totals,
    int* __restrict__ done_ctr)
{
    if (blockIdx.x == NROW / 4) {            // histogram / init block
        __shared__ int lh[64];
        const int tid = threadIdx.x;
        if (tid < 64) lh[tid] = 0;
        __syncthreads();
        for (int i = tid; i < NROW; i += 256)
            atomicAdd(&lh[labels[i]], 1);    // LDS atomics: no XCD ping-pong
        __syncthreads();
        if (tid < 64) hist[tid] = lh[tid];
        if (tid == 64) { totals[0] = 0.f; totals[1] = 0.f; }
        if (tid == 65) { *done_ctr = 0; }
        return;
    }

    const int lane = threadIdx.x & 63;
    const int wave = threadIdx.x >> 6;
    const int row  = blockIdx.x * 4 + wave;

    const float4* zr = (const float4*)(z + (size_t)row * DIM);
    float4 v0 = zr[lane * 2 + 0];
    float4 v1 = zr[lane * 2 + 1];
    float s = v0.x*v0.x + v0.y*v0.y + v0.z*v0.z + v0.w*v0.w
            + v1.x*v1.x + v1.y*v1.y + v1.z*v1.z + v1.w*v1.w;

    union { unsigned char b[8]; int2 v; } pk;
    pk.b[0] = f32_to_e4m3(v0.x); pk.b[1] = f32_to_e4m3(v0.y);
    pk.b[2] = f32_to_e4m3(v0.z); pk.b[3] = f32_to_e4m3(v0.w);
    pk.b[4] = f32_to_e4m3(v1.x); pk.b[5] = f32_to_e4m3(v1.y);
    pk.b[6] = f32_to_e4m3(v1.z); pk.b[7] = f32_to_e4m3(v1.w);
    ((int2*)(zq + (size_t)row * DIM))[lane] = pk.v;   // bytes k..k+7 in order

    #pragma unroll
    for (int sft = 1; sft < 64; sft <<= 1) s += __shfl_xor(s, sft);
    if (lane == 0) sq[row] = s;
}

// ---------------------------------------------------------------------------
// tile: one 128x128 Gram tile (upper triangle) via 16x16x32 FP8 MFMA.
// R15 = R9 verbatim (verified 55.2 µs: XOR-swizzled staging keeps BOTH the
// linear LDS dest AND <=128-B coalesced source — R14's chunk-major broke the
// latter, 4x fetch amplification) + two layout-independent epilogue wins:
// template<DIAG> (only 64/2080 blocks pay the diagonal cmp) and
// neg = tot - pos (one select per element).
// (256,3): 3 blocks/CU (R8's (256,4) spilled). No global atomics.
// ---------------------------------------------------------------------------
template <bool DIAG>
__device__ __forceinline__ void epilogue(
    int tid, int lane, int wm, int wn, int row0, int col0, bool offdiag,
    const f32x4 acc[4][4], const float* __restrict__ sq,
    const int* __restrict__ labels, unsigned char* lds,
    float* __restrict__ partial_pos, float* __restrict__ partial_neg)
{
    const int colbase = col0 + wn * 64;
    const int hi = lane >> 4;
    float csq[4]; int clb[4];
    #pragma unroll
    for (int n = 0; n < 4; ++n) {
        int cg = colbase + n * 16 + (lane & 15);
        csq[n] = sq[cg];
        clb[n] = labels[cg];
    }
    float cpos[4] = {0.f, 0.f, 0.f, 0.f};
    float ctot[4] = {0.f, 0.f, 0.f, 0.f};

    float* rp = (float*)lds;       // [wn*128 + row_local]  256 f
    float* rn = rp + 256;          // 256 f
    float* cp = rp + 512;          // [wm*128 + col_local]  256 f
    float* cn = rp + 768;          // 256 f

    #pragma unroll
    for (int m = 0; m < 4; ++m) {
        #pragma unroll
        for (int r = 0; r < 4; ++r) {
            const int rowl = wm * 64 + m * 16 + hi * 4 + r;
            const int rg = row0 + rowl;
            const float rs = sq[rg];
            const int   rl = labels[rg];
            float pos = 0.f, tot = 0.f;
            #pragma unroll
            for (int n = 0; n < 4; ++n) {
                float d2   = rs + csq[n] - 2.0f * acc[m][n][r];
                float dist = d2 > 0.f ? fast_sqrtf(d2) : 0.f;
                if (DIAG) {
                    int cg = colbase + n * 16 + (lane & 15);
                    if (cg == rg) dist = 0.f;      // exact-zero diagonal
                }
                float dp = (rl == clb[n]) ? dist : 0.f;
                pos += dp;  tot += dist;
                cpos[n] += dp;  ctot[n] += dist;   // column sums (symmetry)
            }
            #pragma unroll
            for (int s = 1; s < 16; s <<= 1) {
                pos += __shfl_xor(pos, s);
                tot += __shfl_xor(tot, s);
            }
            if ((lane & 15) == 0) {
                rp[wn * 128 + rowl] = pos;
                rn[wn * 128 + rowl] = tot - pos;
            }
        }
    }

    #pragma unroll
    for (int n = 0; n < 4; ++n) {
        cpos[n] += __shfl_xor(cpos[n], 16);
        cpos[n] += __shfl_xor(cpos[n], 32);
        ctot[n] += __shfl_xor(ctot[n], 16);
        ctot[n] += __shfl_xor(ctot[n], 32);
        if (lane < 16) {
            int coll = wn * 64 + n * 16 + lane;
            cp[wm * 128 + coll] = cpos[n];
            cn[wm * 128 + coll] = ctot[n] - cpos[n];
        }
    }
    __syncthreads();

    // unique-writer plain stores (no atomics, no zero-init needed)
    const int tn = col0 / BN, tm = row0 / BM;
    if (tid < 128) {
        float p  = rp[tid] + rp[128 + tid];
        float nn = rn[tid] + rn[128 + tid];
        partial_pos[(size_t)tn * NROW + row0 + tid] = p;
        partial_neg[(size_t)tn * NROW + row0 + tid] = nn;
        if (offdiag) {
            float p2 = cp[tid] + cp[128 + tid];
            float n2 = cn[tid] + cn[128 + tid];
            partial_pos[(size_t)tm * NROW + col0 + tid] = p2;
            partial_neg[(size_t)tm * NROW + col0 + tid] = n2;
        }
    }
}

__global__ __launch_bounds__(256, 3) void tile_kernel(
    const unsigned char* __restrict__ zq,
    const float* __restrict__ sq, const int* __restrict__ labels,
    float* __restrict__ partial_pos, float* __restrict__ partial_neg)
{
    __shared__ unsigned char As[BM * BKB];  // 16 KiB
    __shared__ unsigned char Bs[BN * BKB];  // 16 KiB

    const int tid  = threadIdx.x;
    const int lane = tid & 63;
    const int wave = tid >> 6;
    const int wm = wave >> 1;   // 0..1 -> 64-row half
    const int wn = wave & 1;    // 0..1 -> 64-col half

    // XCD-chunked bijective remap (2080 = 8*260), then triangular decode
    const int bid  = (int)blockIdx.x;
    int bidx = (bid & 7) * (NBLK / 8) + (bid >> 3);
    int tm = 0, rem = bidx;
    while (rem >= NT - tm) { rem -= NT - tm; ++tm; }
    const int tn = tm + rem;
    const int row0 = tm * BM;
    const int col0 = tn * BN;
    const bool offdiag = (tm != tn);

    f32x4 acc[4][4];
    #pragma unroll
    for (int m = 0; m < 4; ++m)
        #pragma unroll
        for (int n = 0; n < 4; ++n)
            acc[m][n] = (f32x4){0.f, 0.f, 0.f, 0.f};

    // staging: per K-step, A tile = 128 rows x 128 B = 16 KiB = 4 calls of
    // (256 thr x 16 B); LDS row = r*32 + tid/8; global k pre-swizzled so the
    // XOR-swizzled ds_read sees the right bytes (rule #21). Source stays
    // coalesced: 8 lanes cover the same contiguous 128-B row segment.
    const int srow   = tid >> 3;                       // 0..31
    const int sinner = (tid & 7) << 4;                 // 0..112
    const int kbsw   = sinner ^ ((srow & 7) << 4);     // r*32 -> swz r-invariant
    const unsigned char* baseA = zq + (size_t)(row0 + srow) * DIM + kbsw;
    const unsigned char* baseB = zq + (size_t)(col0 + srow) * DIM + kbsw;

    #pragma unroll 1
    for (int t = 0; t < NTK; ++t) {
        const int k0 = t * BKB;
        #pragma unroll
        for (int r = 0; r < 4; ++r) {
            __builtin_amdgcn_global_load_lds(
                (const __attribute__((address_space(1))) void*)(baseA + (size_t)r * 32 * DIM + k0),
                (__attribute__((address_space(3))) void*)(As + r * 4096 + tid * 16),
                16, 0, 0);
            __builtin_amdgcn_global_load_lds(
                (const __attribute__((address_space(1))) void*)(baseB + (size_t)r * 32 * DIM + k0),
                (__attribute__((address_space(3))) void*)(Bs + r * 4096 + tid * 16),
                16, 0, 0);
        }
        __syncthreads();   // vmcnt(0) drain; hidden by the other 2 blocks/CU

        #pragma unroll
        for (int kk = 0; kk < BKB; kk += 32) {          // 4 x K=32 fp8 MFMA
            const int kbyte = kk + ((lane >> 4) << 3);  // 8-B frag per lane
            long bg[4];
            #pragma unroll
            for (int n = 0; n < 4; ++n) {
                int coll = wn * 64 + n * 16 + (lane & 15);
                bg[n] = *(const long*)(Bs + coll * BKB + (kbyte ^ ((coll & 7) << 4)));
            }
            #pragma unroll
            for (int m = 0; m < 4; ++m) {
                int rowl = wm * 64 + m * 16 + (lane & 15);
                long af = *(const long*)(As + rowl * BKB + (kbyte ^ ((rowl & 7) << 4)));
                #pragma unroll
                for (int n = 0; n < 4; ++n)
                    acc[m][n] = __builtin_amdgcn_mfma_f32_16x16x32_fp8_fp8(
                        af, bg[n], acc[m][n], 0, 0, 0);
            }
        }
        __syncthreads();   // LDS reuse safety for next STAGE
    }

    if (offdiag)
        epilogue<false>(tid, lane, wm, wn, row0, col0, true,  acc, sq, labels,
                        As, partial_pos, partial_neg);
    else
        epilogue<true >(tid, lane, wm, wn, row0, col0, false, acc, sq, labels,
                        As, partial_pos, partial_neg);
}

// ---------------------------------------------------------------------------
// row loss: sum the 64 per-slot partials, margin/relu/reduce; the LAST block
// (device-scope counter) computes the final quotient (saves a dispatch).
// ---------------------------------------------------------------------------
__global__ __launch_bounds__(256) void rowloss_kernel(
    const float* __restrict__ partial_pos, const float* __restrict__ partial_neg,
    const int* __restrict__ labels, const int* __restrict__ hist,
    float* __restrict__ totals, int* __restrict__ done_ctr,
    float* __restrict__ out)
{
    const int i = blockIdx.x * 256 + threadIdx.x;
    float ps = 0.f, ns = 0.f;
    #pragma unroll 8
    for (int s = 0; s < NT; ++s) {
        ps += partial_pos[(size_t)s * NROW + i];
        ns += partial_neg[(size_t)s * NROW + i];
    }
    const float pc = (float)hist[labels[i]];        // includes self
    const float nc = (float)NROW - pc;
    const float pm = ps / fmaxf(pc, 1.f);
    const float nm = ns / fmaxf(nc, 1.f);
    const bool valid = (pc > 1.f) && (nc > 0.f);
    float t = valid ? fmaxf(pm - nm + 1.0f, 0.f) : 0.f;
    float c = valid ? 1.f : 0.f;
    #pragma unroll
    for (int s = 1; s < 64; s <<= 1) {
        t += __shfl_xor(t, s);
        c += __shfl_xor(c, s);
    }
    __shared__ float blk[8];  // 4 waves x {t,c}
    const int wv = threadIdx.x >> 6;
    if ((threadIdx.x & 63) == 0) { blk[wv] = t; blk[4 + wv] = c; }
    __syncthreads();
    if (threadIdx.x == 0) {
        atomicAdd(&totals[0], blk[0] + blk[1] + blk[2] + blk[3]);
        atomicAdd(&totals[1], blk[4] + blk[5] + blk[6] + blk[7]);
        __threadfence();
        int prev = atomicAdd(done_ctr, 1);
        if (prev == (int)gridDim.x - 1) {
            float tt = atomicAdd(&totals[0], 0.f);   // coherent read
            float cc = atomicAdd(&totals[1], 0.f);
            out[0] = tt / fmaxf(cc, 1.f);
        }
    }
}

// ---------------------------------------------------------------------------
extern "C" void kernel_launch(void* const* d_in, const int* in_sizes, int n_in,
                              void* d_out, int out_size, void* d_ws, size_t ws_size,
                              hipStream_t stream) {
    (void)in_sizes; (void)n_in; (void)out_size; (void)ws_size;
    const float* z      = (const float*)d_in[0];
    const int*   labels = (const int*)d_in[1];
    float*       out    = (float*)d_out;

    char* ws = (char*)d_ws;
    float* partial_pos = (float*)(ws);                      // 2 MiB (64 x 8192 f32)
    float* partial_neg = (float*)(ws + 2097152);            // 2 MiB
    int*   hist     = (int*)  (ws + 4194304);               // 256 B
    float* totals   = (float*)(ws + 4194560);               // 8 B
    int*   done_ctr = (int*)  (ws + 4194568);               // 4 B
    unsigned char* zq = (unsigned char*)(ws + 4194816);     // 4 MiB (fp8)
    float* sq       = (float*)(ws + 4194816 + (size_t)NROW * DIM); // 32 KiB

    // no memset: prep's extra block zeroes hist/totals/done_ctr;
    // partials are written exactly once per launch.
    prep_kernel    <<<NROW / 4 + 1, 256, 0, stream>>>(z, labels, zq, sq, hist,
                                                      totals, done_ctr);
    tile_kernel    <<<NBLK, 256, 0, stream>>>(zq, sq, labels, partial_pos, partial_neg);
    rowloss_kernel <<<NROW / 256, 256, 0, stream>>>(partial_pos, partial_neg, labels,
                                                    hist, totals, done_ctr, out);
}

// Round 16
// 72.678 us; speedup vs baseline: 1.7758x; 1.4612x over previous
//
#include <hip/hip_runtime.h>
#include <hip/hip_bf16.h>
#include <hip/hip_fp8.h>
#include <stdint.h>

#define NROW 8192
#define DIM  512
#define BM   128
#define BN   128
#define BKB  128                  // K-step in BYTES (=128 fp8 elements)
#define NTK  (DIM / BKB)          // 4 K-steps
#define NT   (NROW / BM)          // 64 tile rows/cols
#define NBLK (NT * (NT + 1) / 2)  // 2080 upper-triangular tiles (= 8 * 260)

typedef float f32x4 __attribute__((ext_vector_type(4)));

__device__ __forceinline__ float fast_sqrtf(float x) {
    return __builtin_amdgcn_sqrtf(x);   // raw v_sqrt_f32; tolerance is 1.5e-2
}

__device__ __forceinline__ unsigned char f32_to_e4m3(float f) {
    __hip_fp8_e4m3 q(f);                // OCP e4m3fn, RNE + satfinite
    return (unsigned char)q.__x;
}

// ---------------------------------------------------------------------------
// prep: blocks 0..2047: z (fp32) -> zq (fp8 e4m3), sq[i] = ||z_i||^2 (fp32,
// exact norms — only the cross-dot is quantized). block 2048: hist via LDS
// atomics (R7-verified) + zero init (replaces memset dispatch).
// ---------------------------------------------------------------------------
__global__ __launch_bounds__(256) void prep_kernel(
    const float* __restrict__ z, const int* __restrict__ labels,
    unsigned char* __restrict__ zq, float* __restrict__ sq,
    int* __restrict__ hist, float* __restrict__ totals,
    int* __restrict__ done_ctr)
{
    if (blockIdx.x == NROW / 4) {            // histogram / init block
        __shared__ int lh[64];
        const int tid = threadIdx.x;
        if (tid < 64) lh[tid] = 0;
        __syncthreads();
        for (int i = tid; i < NROW; i += 256)
            atomicAdd(&lh[labels[i]], 1);    // LDS atomics: no XCD ping-pong
        __syncthreads();
        if (tid < 64) hist[tid] = lh[tid];
        if (tid == 64) { totals[0] = 0.f; totals[1] = 0.f; }
        if (tid == 65) { *done_ctr = 0; }
        return;
    }

    const int lane = threadIdx.x & 63;
    const int wave = threadIdx.x >> 6;
    const int row  = blockIdx.x * 4 + wave;

    const float4* zr = (const float4*)(z + (size_t)row * DIM);
    float4 v0 = zr[lane * 2 + 0];
    float4 v1 = zr[lane * 2 + 1];
    float s = v0.x*v0.x + v0.y*v0.y + v0.z*v0.z + v0.w*v0.w
            + v1.x*v1.x + v1.y*v1.y + v1.z*v1.z + v1.w*v1.w;

    union { unsigned char b[8]; int2 v; } pk;
    pk.b[0] = f32_to_e4m3(v0.x); pk.b[1] = f32_to_e4m3(v0.y);
    pk.b[2] = f32_to_e4m3(v0.z); pk.b[3] = f32_to_e4m3(v0.w);
    pk.b[4] = f32_to_e4m3(v1.x); pk.b[5] = f32_to_e4m3(v1.y);
    pk.b[6] = f32_to_e4m3(v1.z); pk.b[7] = f32_to_e4m3(v1.w);
    ((int2*)(zq + (size_t)row * DIM))[lane] = pk.v;   // bytes k..k+7 in order

    #pragma unroll
    for (int sft = 1; sft < 64; sft <<= 1) s += __shfl_xor(s, sft);
    if (lane == 0) sq[row] = s;
}

// ---------------------------------------------------------------------------
// tile: one 128x128 Gram tile (upper triangle) via 16x16x32 FP8 MFMA.
// R16 = R9 VERBATIM (benched 55.2 µs tile / 72.4 total, FETCH 14 MB).
// R15 lesson: wrapping the epilogue in a function taking acc[4][4] by
// pointer made the accumulator addressable -> scratch spill (FETCH 14->76
// MB, +33 µs). Keep the epilogue inline in the kernel body; never pass acc
// across a function boundary (rule #20 in parameter form).
// fp8 e4m3 staging, XOR-swizzled source + ds_read (rule #21), linear LDS
// dest, coalesced <=128-B source. (256,3): 3 blocks/CU. No global atomics.
// ---------------------------------------------------------------------------
__global__ __launch_bounds__(256, 3) void tile_kernel(
    const unsigned char* __restrict__ zq,
    const float* __restrict__ sq, const int* __restrict__ labels,
    float* __restrict__ partial_pos, float* __restrict__ partial_neg)
{
    __shared__ unsigned char As[BM * BKB];  // 16 KiB
    __shared__ unsigned char Bs[BN * BKB];  // 16 KiB

    const int tid  = threadIdx.x;
    const int lane = tid & 63;
    const int wave = tid >> 6;
    const int wm = wave >> 1;   // 0..1 -> 64-row half
    const int wn = wave & 1;    // 0..1 -> 64-col half

    // XCD-chunked bijective remap (2080 = 8*260), then triangular decode
    const int bid  = (int)blockIdx.x;
    int bidx = (bid & 7) * (NBLK / 8) + (bid >> 3);
    int tm = 0, rem = bidx;
    while (rem >= NT - tm) { rem -= NT - tm; ++tm; }
    const int tn = tm + rem;
    const int row0 = tm * BM;
    const int col0 = tn * BN;
    const bool offdiag = (tm != tn);

    f32x4 acc[4][4];
    #pragma unroll
    for (int m = 0; m < 4; ++m)
        #pragma unroll
        for (int n = 0; n < 4; ++n)
            acc[m][n] = (f32x4){0.f, 0.f, 0.f, 0.f};

    // staging: per K-step, A tile = 128 rows x 128 B = 16 KiB = 4 calls of
    // (256 thr x 16 B); LDS row = r*32 + tid/8; global k pre-swizzled so the
    // XOR-swizzled ds_read sees the right bytes (rule #21).
    const int srow   = tid >> 3;                       // 0..31
    const int sinner = (tid & 7) << 4;                 // 0..112
    const int kbsw   = sinner ^ ((srow & 7) << 4);     // r*32 -> swz r-invariant
    const unsigned char* baseA = zq + (size_t)(row0 + srow) * DIM + kbsw;
    const unsigned char* baseB = zq + (size_t)(col0 + srow) * DIM + kbsw;

    #pragma unroll 1
    for (int t = 0; t < NTK; ++t) {
        const int k0 = t * BKB;
        #pragma unroll
        for (int r = 0; r < 4; ++r) {
            __builtin_amdgcn_global_load_lds(
                (const __attribute__((address_space(1))) void*)(baseA + (size_t)r * 32 * DIM + k0),
                (__attribute__((address_space(3))) void*)(As + r * 4096 + tid * 16),
                16, 0, 0);
            __builtin_amdgcn_global_load_lds(
                (const __attribute__((address_space(1))) void*)(baseB + (size_t)r * 32 * DIM + k0),
                (__attribute__((address_space(3))) void*)(Bs + r * 4096 + tid * 16),
                16, 0, 0);
        }
        __syncthreads();   // vmcnt(0) drain; hidden by the other 2 blocks/CU

        #pragma unroll
        for (int kk = 0; kk < BKB; kk += 32) {          // 4 x K=32 fp8 MFMA
            const int kbyte = kk + ((lane >> 4) << 3);  // 8-B frag per lane
            long bg[4];
            #pragma unroll
            for (int n = 0; n < 4; ++n) {
                int coll = wn * 64 + n * 16 + (lane & 15);
                bg[n] = *(const long*)(Bs + coll * BKB + (kbyte ^ ((coll & 7) << 4)));
            }
            #pragma unroll
            for (int m = 0; m < 4; ++m) {
                int rowl = wm * 64 + m * 16 + (lane & 15);
                long af = *(const long*)(As + rowl * BKB + (kbyte ^ ((rowl & 7) << 4)));
                #pragma unroll
                for (int n = 0; n < 4; ++n)
                    acc[m][n] = __builtin_amdgcn_mfma_f32_16x16x32_fp8_fp8(
                        af, bg[n], acc[m][n], 0, 0, 0);
            }
        }
        __syncthreads();   // LDS reuse safety for next STAGE
    }

    // ---- fused epilogue (inline in kernel body — R15 lesson) ----
    // C/D map: col = lane&15, row = (lane>>4)*4 + r  (m89-verified)
    const int colbase = col0 + wn * 64;
    const int hi = lane >> 4;
    float csq[4]; int clb[4];
    #pragma unroll
    for (int n = 0; n < 4; ++n) {
        int cg = colbase + n * 16 + (lane & 15);
        csq[n] = sq[cg];
        clb[n] = labels[cg];
    }
    float cpos[4] = {0.f, 0.f, 0.f, 0.f};
    float cneg[4] = {0.f, 0.f, 0.f, 0.f};

    // LDS cross-wave reduction scratch (reuses As; sync'd above)
    float* rp = (float*)As;        // [wn*128 + row_local]  256 f
    float* rn = rp + 256;          // 256 f
    float* cp = rp + 512;          // [wm*128 + col_local]  256 f
    float* cn = rp + 768;          // 256 f

    #pragma unroll
    for (int m = 0; m < 4; ++m) {
        #pragma unroll
        for (int r = 0; r < 4; ++r) {
            const int rowl = wm * 64 + m * 16 + hi * 4 + r;
            const int rg = row0 + rowl;
            const float rs = sq[rg];
            const int   rl = labels[rg];
            float pos = 0.f, neg = 0.f;
            #pragma unroll
            for (int n = 0; n < 4; ++n) {
                float d2   = rs + csq[n] - 2.0f * acc[m][n][r];
                float dist = d2 > 0.f ? fast_sqrtf(d2) : 0.f;
                int cg = colbase + n * 16 + (lane & 15);
                if (cg == rg) dist = 0.f;          // exact-zero diagonal
                bool same = (rl == clb[n]);
                float dp = same ? dist : 0.f;
                float dn = same ? 0.f : dist;
                pos += dp;  neg += dn;
                cpos[n] += dp;  cneg[n] += dn;     // column sums (symmetry)
            }
            #pragma unroll
            for (int s = 1; s < 16; s <<= 1) {
                pos += __shfl_xor(pos, s);
                neg += __shfl_xor(neg, s);
            }
            if ((lane & 15) == 0) {
                rp[wn * 128 + rowl] = pos;
                rn[wn * 128 + rowl] = neg;
            }
        }
    }

    #pragma unroll
    for (int n = 0; n < 4; ++n) {
        cpos[n] += __shfl_xor(cpos[n], 16);
        cpos[n] += __shfl_xor(cpos[n], 32);
        cneg[n] += __shfl_xor(cneg[n], 16);
        cneg[n] += __shfl_xor(cneg[n], 32);
        if (lane < 16) {
            int coll = wn * 64 + n * 16 + lane;
            cp[wm * 128 + coll] = cpos[n];
            cn[wm * 128 + coll] = cneg[n];
        }
    }
    __syncthreads();

    // unique-writer plain stores (no atomics, no zero-init needed)
    if (tid < 128) {
        float p  = rp[tid] + rp[128 + tid];
        float nn = rn[tid] + rn[128 + tid];
        partial_pos[(size_t)tn * NROW + row0 + tid] = p;
        partial_neg[(size_t)tn * NROW + row0 + tid] = nn;
        if (offdiag) {
            float p2 = cp[tid] + cp[128 + tid];
            float n2 = cn[tid] + cn[128 + tid];
            partial_pos[(size_t)tm * NROW + col0 + tid] = p2;
            partial_neg[(size_t)tm * NROW + col0 + tid] = n2;
        }
    }
}

// ---------------------------------------------------------------------------
// row loss: sum the 64 per-slot partials, margin/relu/reduce; the LAST block
// (device-scope counter) computes the final quotient (saves a dispatch).
// ---------------------------------------------------------------------------
__global__ __launch_bounds__(256) void rowloss_kernel(
    const float* __restrict__ partial_pos, const float* __restrict__ partial_neg,
    const int* __restrict__ labels, const int* __restrict__ hist,
    float* __restrict__ totals, int* __restrict__ done_ctr,
    float* __restrict__ out)
{
    const int i = blockIdx.x * 256 + threadIdx.x;
    float ps = 0.f, ns = 0.f;
    #pragma unroll 8
    for (int s = 0; s < NT; ++s) {
        ps += partial_pos[(size_t)s * NROW + i];
        ns += partial_neg[(size_t)s * NROW + i];
    }
    const float pc = (float)hist[labels[i]];        // includes self
    const float nc = (float)NROW - pc;
    const float pm = ps / fmaxf(pc, 1.f);
    const float nm = ns / fmaxf(nc, 1.f);
    const bool valid = (pc > 1.f) && (nc > 0.f);
    float t = valid ? fmaxf(pm - nm + 1.0f, 0.f) : 0.f;
    float c = valid ? 1.f : 0.f;
    #pragma unroll
    for (int s = 1; s < 64; s <<= 1) {
        t += __shfl_xor(t, s);
        c += __shfl_xor(c, s);
    }
    __shared__ float blk[8];  // 4 waves x {t,c}
    const int wv = threadIdx.x >> 6;
    if ((threadIdx.x & 63) == 0) { blk[wv] = t; blk[4 + wv] = c; }
    __syncthreads();
    if (threadIdx.x == 0) {
        atomicAdd(&totals[0], blk[0] + blk[1] + blk[2] + blk[3]);
        atomicAdd(&totals[1], blk[4] + blk[5] + blk[6] + blk[7]);
        __threadfence();
        int prev = atomicAdd(done_ctr, 1);
        if (prev == (int)gridDim.x - 1) {
            float tt = atomicAdd(&totals[0], 0.f);   // coherent read
            float cc = atomicAdd(&totals[1], 0.f);
            out[0] = tt / fmaxf(cc, 1.f);
        }
    }
}

// ---------------------------------------------------------------------------
extern "C" void kernel_launch(void* const* d_in, const int* in_sizes, int n_in,
                              void* d_out, int out_size, void* d_ws, size_t ws_size,
                              hipStream_t stream) {
    (void)in_sizes; (void)n_in; (void)out_size; (void)ws_size;
    const float* z      = (const float*)d_in[0];
    const int*   labels = (const int*)d_in[1];
    float*       out    = (float*)d_out;

    char* ws = (char*)d_ws;
    float* partial_pos = (float*)(ws);                      // 2 MiB (64 x 8192 f32)
    float* partial_neg = (float*)(ws + 2097152);            // 2 MiB
    int*   hist     = (int*)  (ws + 4194304);               // 256 B
    float* totals   = (float*)(ws + 4194560);               // 8 B
    int*   done_ctr = (int*)  (ws + 4194568);               // 4 B
    unsigned char* zq = (unsigned char*)(ws + 4194816);     // 4 MiB (fp8)
    float* sq       = (float*)(ws + 4194816 + (size_t)NROW * DIM); // 32 KiB

    // no memset: prep's extra block zeroes hist/totals/done_ctr;
    // partials are written exactly once per launch.
    prep_kernel    <<<NROW / 4 + 1, 256, 0, stream>>>(z, labels, zq, sq, hist,
                                                      totals, done_ctr);
    tile_kernel    <<<NBLK, 256, 0, stream>>>(zq, sq, labels, partial_pos, partial_neg);
    rowloss_kernel <<<NROW / 256, 256, 0, stream>>>(partial_pos, partial_neg, labels,
                                                    hist, totals, done_ctr, out);
}

// Round 17
// 64.802 us; speedup vs baseline: 1.9916x; 1.1215x over previous
//
#include <hip/hip_runtime.h>
#include <hip/hip_bf16.h>
#include <hip/hip_fp8.h>
#include <stdint.h>

#define NROW 8192
#define DIM  512
#define BM   128
#define BN   128
#define BKB  128                  // K-step in BYTES (=128 fp8 elements)
#define NTK  (DIM / BKB)          // 4 K-steps
#define NT   (NROW / BM)          // 64 tile rows/cols
#define NBLK (NT * (NT + 1) / 2)  // 2080 upper-triangular tiles (= 8 * 260)

typedef float f32x4 __attribute__((ext_vector_type(4)));
typedef int   i32x4 __attribute__((ext_vector_type(4)));
typedef int   i32x8 __attribute__((ext_vector_type(8)));

__device__ __forceinline__ float fast_sqrtf(float x) {
    return __builtin_amdgcn_sqrtf(x);   // raw v_sqrt_f32; tolerance is 1.5e-2
}

__device__ __forceinline__ unsigned char f32_to_e4m3(float f) {
    __hip_fp8_e4m3 q(f);                // OCP e4m3fn, RNE + satfinite
    return (unsigned char)q.__x;
}

// ---------------------------------------------------------------------------
// prep: blocks 0..2047: z (fp32) -> zq (fp8 e4m3), sq[i] = ||z_i||^2 (fp32,
// exact norms — only the cross-dot is quantized). block 2048: hist via LDS
// atomics (R7-verified) + zero init (replaces memset dispatch).
// ---------------------------------------------------------------------------
__global__ __launch_bounds__(256) void prep_kernel(
    const float* __restrict__ z, const int* __restrict__ labels,
    unsigned char* __restrict__ zq, float* __restrict__ sq,
    int* __restrict__ hist, float* __restrict__ totals,
    int* __restrict__ done_ctr)
{
    if (blockIdx.x == NROW / 4) {            // histogram / init block
        __shared__ int lh[64];
        const int tid = threadIdx.x;
        if (tid < 64) lh[tid] = 0;
        __syncthreads();
        for (int i = tid; i < NROW; i += 256)
            atomicAdd(&lh[labels[i]], 1);    // LDS atomics: no XCD ping-pong
        __syncthreads();
        if (tid < 64) hist[tid] = lh[tid];
        if (tid == 64) { totals[0] = 0.f; totals[1] = 0.f; }
        if (tid == 65) { *done_ctr = 0; }
        return;
    }

    const int lane = threadIdx.x & 63;
    const int wave = threadIdx.x >> 6;
    const int row  = blockIdx.x * 4 + wave;

    const float4* zr = (const float4*)(z + (size_t)row * DIM);
    float4 v0 = zr[lane * 2 + 0];
    float4 v1 = zr[lane * 2 + 1];
    float s = v0.x*v0.x + v0.y*v0.y + v0.z*v0.z + v0.w*v0.w
            + v1.x*v1.x + v1.y*v1.y + v1.z*v1.z + v1.w*v1.w;

    union { unsigned char b[8]; int2 v; } pk;
    pk.b[0] = f32_to_e4m3(v0.x); pk.b[1] = f32_to_e4m3(v0.y);
    pk.b[2] = f32_to_e4m3(v0.z); pk.b[3] = f32_to_e4m3(v0.w);
    pk.b[4] = f32_to_e4m3(v1.x); pk.b[5] = f32_to_e4m3(v1.y);
    pk.b[6] = f32_to_e4m3(v1.z); pk.b[7] = f32_to_e4m3(v1.w);
    ((int2*)(zq + (size_t)row * DIM))[lane] = pk.v;   // bytes k..k+7 in order

    #pragma unroll
    for (int sft = 1; sft < 64; sft <<= 1) s += __shfl_xor(s, sft);
    if (lane == 0) sq[row] = s;
}

// ---------------------------------------------------------------------------
// tile: one 128x128 Gram tile (upper triangle) via MX-scaled 16x16x128 FP8
// MFMA with scale=1.0 (e8m0 127) — numerically identical to the R16 fp8 dot.
// R17 change (vs R16, which is otherwise verbatim): one MFMA consumes the
// whole 128-B K-chunk -> per K-step 64->16 MFMA, 32 b64 -> 24 b128 ds_reads,
// and ALL ds_read addressing folds to 4 base VGPRs + immediate offsets
// (lane fragment = k [hi*32, hi*32+32) = two aligned b128 at per-lane-const
// XOR'd offsets). Attacks the diagnosed issue-pressure/convoy bound.
// Staging/swizzle/epilogue/C-D map unchanged (shape-determined layout).
// (256,3): 3 blocks/CU. No global atomics. acc never passed to a function
// (rule #20, R15 lesson).
// ---------------------------------------------------------------------------
__global__ __launch_bounds__(256, 3) void tile_kernel(
    const unsigned char* __restrict__ zq,
    const float* __restrict__ sq, const int* __restrict__ labels,
    float* __restrict__ partial_pos, float* __restrict__ partial_neg)
{
    __shared__ unsigned char As[BM * BKB];  // 16 KiB
    __shared__ unsigned char Bs[BN * BKB];  // 16 KiB

    const int tid  = threadIdx.x;
    const int lane = tid & 63;
    const int wave = tid >> 6;
    const int wm = wave >> 1;   // 0..1 -> 64-row half
    const int wn = wave & 1;    // 0..1 -> 64-col half

    // XCD-chunked bijective remap (2080 = 8*260), then triangular decode
    const int bid  = (int)blockIdx.x;
    int bidx = (bid & 7) * (NBLK / 8) + (bid >> 3);
    int tm = 0, rem = bidx;
    while (rem >= NT - tm) { rem -= NT - tm; ++tm; }
    const int tn = tm + rem;
    const int row0 = tm * BM;
    const int col0 = tn * BN;
    const bool offdiag = (tm != tn);

    f32x4 acc[4][4];
    #pragma unroll
    for (int m = 0; m < 4; ++m)
        #pragma unroll
        for (int n = 0; n < 4; ++n)
            acc[m][n] = (f32x4){0.f, 0.f, 0.f, 0.f};

    // staging (verbatim R16): LDS row = r*32 + tid/8; global k pre-swizzled
    // so the XOR-swizzled ds_read sees the right bytes (rule #21).
    const int srow   = tid >> 3;                       // 0..31
    const int sinner = (tid & 7) << 4;                 // 0..112
    const int kbsw   = sinner ^ ((srow & 7) << 4);     // r*32 -> swz r-invariant
    const unsigned char* baseA = zq + (size_t)(row0 + srow) * DIM + kbsw;
    const unsigned char* baseB = zq + (size_t)(col0 + srow) * DIM + kbsw;

    // per-lane-constant fragment bases: rowl&7 == lane&7 for every m (m*16,
    // wm*64 are 0 mod 8), so the XOR operand is fixed per lane and m/n move
    // in +2048-byte immediates.
    const int swz  = (lane & 7) << 4;
    const int hi32 = (lane >> 4) << 5;
    const unsigned char* apc0 = As + (wm * 64 + (lane & 15)) * BKB + ((hi32 +  0) ^ swz);
    const unsigned char* apc1 = As + (wm * 64 + (lane & 15)) * BKB + ((hi32 + 16) ^ swz);
    const unsigned char* bpc0 = Bs + (wn * 64 + (lane & 15)) * BKB + ((hi32 +  0) ^ swz);
    const unsigned char* bpc1 = Bs + (wn * 64 + (lane & 15)) * BKB + ((hi32 + 16) ^ swz);

    // assemble a 32-B fragment (k ascending by construction) from two b128s
#define FRAG(pc0, pc1, off)                                                    \
    __builtin_shufflevector(*(const i32x4*)((pc0) + (off)),                    \
                            *(const i32x4*)((pc1) + (off)), 0, 1, 2, 3, 4, 5, 6, 7)

#define MFMA128(a, b, c)                                                       \
    __builtin_amdgcn_mfma_scale_f32_16x16x128_f8f6f4(                          \
        (a), (b), (c), 0, 0, 0, 0x7F7F7F7F, 0, 0x7F7F7F7F)

    #pragma unroll 1
    for (int t = 0; t < NTK; ++t) {
        const int k0 = t * BKB;
        #pragma unroll
        for (int r = 0; r < 4; ++r) {
            __builtin_amdgcn_global_load_lds(
                (const __attribute__((address_space(1))) void*)(baseA + (size_t)r * 32 * DIM + k0),
                (__attribute__((address_space(3))) void*)(As + r * 4096 + tid * 16),
                16, 0, 0);
            __builtin_amdgcn_global_load_lds(
                (const __attribute__((address_space(1))) void*)(baseB + (size_t)r * 32 * DIM + k0),
                (__attribute__((address_space(3))) void*)(Bs + r * 4096 + tid * 16),
                16, 0, 0);
        }
        __syncthreads();   // vmcnt(0) drain; hidden by the other 2 blocks/CU

        #pragma unroll
        for (int p = 0; p < 2; ++p) {       // n-pairs: bounded reg pressure
            i32x8 bg0 = FRAG(bpc0, bpc1, (2 * p    ) * 2048);
            i32x8 bg1 = FRAG(bpc0, bpc1, (2 * p + 1) * 2048);
            #pragma unroll
            for (int m = 0; m < 4; ++m) {
                i32x8 af = FRAG(apc0, apc1, m * 2048);
                acc[m][2 * p    ] = MFMA128(af, bg0, acc[m][2 * p    ]);
                acc[m][2 * p + 1] = MFMA128(af, bg1, acc[m][2 * p + 1]);
            }
        }
        __syncthreads();   // LDS reuse safety for next STAGE
    }
#undef FRAG
#undef MFMA128

    // ---- fused epilogue (inline in kernel body — R15 lesson) ----
    // C/D map: col = lane&15, row = (lane>>4)*4 + r  (m89-verified;
    // shape-determined, dtype/scale-independent)
    const int colbase = col0 + wn * 64;
    const int hi = lane >> 4;
    float csq[4]; int clb[4];
    #pragma unroll
    for (int n = 0; n < 4; ++n) {
        int cg = colbase + n * 16 + (lane & 15);
        csq[n] = sq[cg];
        clb[n] = labels[cg];
    }
    float cpos[4] = {0.f, 0.f, 0.f, 0.f};
    float cneg[4] = {0.f, 0.f, 0.f, 0.f};

    // LDS cross-wave reduction scratch (reuses As; sync'd above)
    float* rp = (float*)As;        // [wn*128 + row_local]  256 f
    float* rn = rp + 256;          // 256 f
    float* cp = rp + 512;          // [wm*128 + col_local]  256 f
    float* cn = rp + 768;          // 256 f

    #pragma unroll
    for (int m = 0; m < 4; ++m) {
        #pragma unroll
        for (int r = 0; r < 4; ++r) {
            const int rowl = wm * 64 + m * 16 + hi * 4 + r;
            const int rg = row0 + rowl;
            const float rs = sq[rg];
            const int   rl = labels[rg];
            float pos = 0.f, neg = 0.f;
            #pragma unroll
            for (int n = 0; n < 4; ++n) {
                float d2   = rs + csq[n] - 2.0f * acc[m][n][r];
                float dist = d2 > 0.f ? fast_sqrtf(d2) : 0.f;
                int cg = colbase + n * 16 + (lane & 15);
                if (cg == rg) dist = 0.f;          // exact-zero diagonal
                bool same = (rl == clb[n]);
                float dp = same ? dist : 0.f;
                float dn = same ? 0.f : dist;
                pos += dp;  neg += dn;
                cpos[n] += dp;  cneg[n] += dn;     // column sums (symmetry)
            }
            #pragma unroll
            for (int s = 1; s < 16; s <<= 1) {
                pos += __shfl_xor(pos, s);
                neg += __shfl_xor(neg, s);
            }
            if ((lane & 15) == 0) {
                rp[wn * 128 + rowl] = pos;
                rn[wn * 128 + rowl] = neg;
            }
        }
    }

    #pragma unroll
    for (int n = 0; n < 4; ++n) {
        cpos[n] += __shfl_xor(cpos[n], 16);
        cpos[n] += __shfl_xor(cpos[n], 32);
        cneg[n] += __shfl_xor(cneg[n], 16);
        cneg[n] += __shfl_xor(cneg[n], 32);
        if (lane < 16) {
            int coll = wn * 64 + n * 16 + lane;
            cp[wm * 128 + coll] = cpos[n];
            cn[wm * 128 + coll] = cneg[n];
        }
    }
    __syncthreads();

    // unique-writer plain stores (no atomics, no zero-init needed)
    if (tid < 128) {
        float p  = rp[tid] + rp[128 + tid];
        float nn = rn[tid] + rn[128 + tid];
        partial_pos[(size_t)tn * NROW + row0 + tid] = p;
        partial_neg[(size_t)tn * NROW + row0 + tid] = nn;
        if (offdiag) {
            float p2 = cp[tid] + cp[128 + tid];
            float n2 = cn[tid] + cn[128 + tid];
            partial_pos[(size_t)tm * NROW + col0 + tid] = p2;
            partial_neg[(size_t)tm * NROW + col0 + tid] = n2;
        }
    }
}

// ---------------------------------------------------------------------------
// row loss: sum the 64 per-slot partials, margin/relu/reduce; the LAST block
// (device-scope counter) computes the final quotient (saves a dispatch).
// ---------------------------------------------------------------------------
__global__ __launch_bounds__(256) void rowloss_kernel(
    const float* __restrict__ partial_pos, const float* __restrict__ partial_neg,
    const int* __restrict__ labels, const int* __restrict__ hist,
    float* __restrict__ totals, int* __restrict__ done_ctr,
    float* __restrict__ out)
{
    const int i = blockIdx.x * 256 + threadIdx.x;
    float ps = 0.f, ns = 0.f;
    #pragma unroll 8
    for (int s = 0; s < NT; ++s) {
        ps += partial_pos[(size_t)s * NROW + i];
        ns += partial_neg[(size_t)s * NROW + i];
    }
    const float pc = (float)hist[labels[i]];        // includes self
    const float nc = (float)NROW - pc;
    const float pm = ps / fmaxf(pc, 1.f);
    const float nm = ns / fmaxf(nc, 1.f);
    const bool valid = (pc > 1.f) && (nc > 0.f);
    float t = valid ? fmaxf(pm - nm + 1.0f, 0.f) : 0.f;
    float c = valid ? 1.f : 0.f;
    #pragma unroll
    for (int s = 1; s < 64; s <<= 1) {
        t += __shfl_xor(t, s);
        c += __shfl_xor(c, s);
    }
    __shared__ float blk[8];  // 4 waves x {t,c}
    const int wv = threadIdx.x >> 6;
    if ((threadIdx.x & 63) == 0) { blk[wv] = t; blk[4 + wv] = c; }
    __syncthreads();
    if (threadIdx.x == 0) {
        atomicAdd(&totals[0], blk[0] + blk[1] + blk[2] + blk[3]);
        atomicAdd(&totals[1], blk[4] + blk[5] + blk[6] + blk[7]);
        __threadfence();
        int prev = atomicAdd(done_ctr, 1);
        if (prev == (int)gridDim.x - 1) {
            float tt = atomicAdd(&totals[0], 0.f);   // coherent read
            float cc = atomicAdd(&totals[1], 0.f);
            out[0] = tt / fmaxf(cc, 1.f);
        }
    }
}

// ---------------------------------------------------------------------------
extern "C" void kernel_launch(void* const* d_in, const int* in_sizes, int n_in,
                              void* d_out, int out_size, void* d_ws, size_t ws_size,
                              hipStream_t stream) {
    (void)in_sizes; (void)n_in; (void)out_size; (void)ws_size;
    const float* z      = (const float*)d_in[0];
    const int*   labels = (const int*)d_in[1];
    float*       out    = (float*)d_out;

    char* ws = (char*)d_ws;
    float* partial_pos = (float*)(ws);                      // 2 MiB (64 x 8192 f32)
    float* partial_neg = (float*)(ws + 2097152);            // 2 MiB
    int*   hist     = (int*)  (ws + 4194304);               // 256 B
    float* totals   = (float*)(ws + 4194560);               // 8 B
    int*   done_ctr = (int*)  (ws + 4194568);               // 4 B
    unsigned char* zq = (unsigned char*)(ws + 4194816);     // 4 MiB (fp8)
    float* sq       = (float*)(ws + 4194816 + (size_t)NROW * DIM); // 32 KiB

    // no memset: prep's extra block zeroes hist/totals/done_ctr;
    // partials are written exactly once per launch.
    prep_kernel    <<<NROW / 4 + 1, 256, 0, stream>>>(z, labels, zq, sq, hist,
                                                      totals, done_ctr);
    tile_kernel    <<<NBLK, 256, 0, stream>>>(zq, sq, labels, partial_pos, partial_neg);
    rowloss_kernel <<<NROW / 256, 256, 0, stream>>>(partial_pos, partial_neg, labels,
                                                    hist, totals, done_ctr, out);
}